// Round 11
// baseline (2490.326 us; speedup 1.0000x reference)
//
#include <hip/hip_runtime.h>

typedef __attribute__((ext_vector_type(8))) short bf16x8;
typedef __attribute__((ext_vector_type(4))) float f32x4;
typedef __attribute__((ext_vector_type(16))) float f32x16;

// B=64, T=512, D=256, H=512, L=4, 4H=2048
// 32 wgs per layer (16 hcols each), 256 threads = 4 waves per wg. Grid 128.
// v11: mfma_f32_32x32x16_bf16 -> 2x FLOP per operand byte; wave (vm,vn) owns
// one 32x32 z-tile (vm = batch half, vn = gate pair). Gate math via LDS zt
// exchange. Sync protocol identical to the passing round-9 kernel.
#define WPL 32
#define NT 256
#define RING 8

__device__ __forceinline__ unsigned short f2bf(float f) {
  unsigned int u = __float_as_uint(f);
  u += 0x7FFFu + ((u >> 16) & 1u);
  return (unsigned short)(u >> 16);
}
__device__ __forceinline__ float sigmoid_fast(float x) {
  return __builtin_amdgcn_rcpf(1.0f + __builtin_amdgcn_exp2f(-1.4426950408889634f * x));
}
__device__ __forceinline__ float tanh_fast(float x) {
  return 1.0f - 2.0f * __builtin_amdgcn_rcpf(
                           1.0f + __builtin_amdgcn_exp2f(2.885390081777927f * x));
}
__device__ __forceinline__ void wait_vm0() {
  asm volatile("s_waitcnt vmcnt(0)" ::: "memory");
  __builtin_amdgcn_sched_barrier(0);
}
#define WAITVM(N)                                         \
  do {                                                    \
    asm volatile("s_waitcnt vmcnt(" #N ")" ::: "memory"); \
    __builtin_amdgcn_sched_barrier(0);                    \
  } while (0)

// MODE: 0 = plain cached (read-only x), 2 = sc0 sc1 (LLC coherent h)
template <int MODE>
__device__ __forceinline__ void ldA(bf16x8& d, int voff, const unsigned short* base) {
  if constexpr (MODE == 0)
    asm volatile("global_load_dwordx4 %0, %1, %2"
                 : "=v"(d) : "v"(voff), "s"(base));
  else
    asm volatile("global_load_dwordx4 %0, %1, %2 sc0 sc1"
                 : "=v"(d) : "v"(voff), "s"(base));
}
__device__ __forceinline__ unsigned ld_flag(const unsigned* p) {
  unsigned v;
  asm volatile("global_load_dword %0, %1, off sc0 sc1\n\ts_waitcnt vmcnt(0)"
               : "=v"(v) : "v"(p) : "memory");
  return v;
}
__device__ __forceinline__ void st16_coh(void* p, f32x4 v) {
  asm volatile("global_store_dwordx4 %0, %1, off sc0 sc1" :: "v"(p), "v"(v) : "memory");
}
__device__ __forceinline__ void st4_coh(void* p, unsigned v) {
  asm volatile("global_store_dword %0, %1, off sc0 sc1" :: "v"(p), "v"(v) : "memory");
}

// ---------------- prep kernels ----------------

// x [B,T,D] f32 -> xfrag [T][ks(16)][vm(2)][lane(64)][e(8)] bf16:
// value(b = vm*32 + (lane&31), d = ks*16 + (lane>>5)*8 + e)
__global__ void cvt_x_kernel(const float* __restrict__ x,
                             unsigned short* __restrict__ xf) {
  int tid = blockIdx.x * 256 + threadIdx.x;  // 1,048,576
  int t     = tid >> 11;
  int inner = tid & 2047;                    // ((ks*2+vm)*64 + lane)
  int lane  = inner & 63;
  int vm    = (inner >> 6) & 1;
  int ks    = inner >> 7;
  int b = vm * 32 + (lane & 31);
  int d = ks * 16 + (lane >> 5) * 8;
  const float* s = x + ((size_t)b * 512 + t) * 256 + d;
  f32x4 v0 = *(const f32x4*)s;
  f32x4 v1 = *(const f32x4*)(s + 4);
  bf16x8 o;
  o[0] = (short)f2bf(v0[0]); o[1] = (short)f2bf(v0[1]);
  o[2] = (short)f2bf(v0[2]); o[3] = (short)f2bf(v0[3]);
  o[4] = (short)f2bf(v1[0]); o[5] = (short)f2bf(v1[1]);
  o[6] = (short)f2bf(v1[2]); o[7] = (short)f2bf(v1[3]);
  *(bf16x8*)(xf + (size_t)t * 16384 + (size_t)inner * 8) = o;
}

// W/U f32 -> wfrag [w(32)][vn(2)][c(C2)][lane(64)][e(8)] bf16:
// zz = vn*32 + (lane&31); row = (zz>>4)*512 + w*16 + (zz&15);
// k = c*16 + (lane>>5)*8 + e
__global__ void cvt_w_kernel(const float* __restrict__ W,
                             const float* __restrict__ U,
                             unsigned short* __restrict__ dst,
                             int C2, int split) {
  int tid = blockIdx.x * 256 + threadIdx.x;
  int lane = tid & 63;
  int c    = (tid >> 6) % C2;
  int rest = tid / (64 * C2);
  int vn = rest & 1;
  int w  = rest >> 1;
  int zz = vn * 32 + (lane & 31);
  int row = (zz >> 4) * 512 + w * 16 + (zz & 15);
  int k   = c * 16 + (lane >> 5) * 8;
  const float* s = (k < split) ? (W + (size_t)row * split + k)
                               : (U + (size_t)row * 512 + (k - split));
  f32x4 v0 = *(const f32x4*)s;
  f32x4 v1 = *(const f32x4*)(s + 4);
  bf16x8 o;
  o[0] = (short)f2bf(v0[0]); o[1] = (short)f2bf(v0[1]);
  o[2] = (short)f2bf(v0[2]); o[3] = (short)f2bf(v0[3]);
  o[4] = (short)f2bf(v1[0]); o[5] = (short)f2bf(v1[1]);
  o[6] = (short)f2bf(v1[2]); o[7] = (short)f2bf(v1[3]);
  *(bf16x8*)(dst + (size_t)tid * 8) = o;
}

__global__ void bias_kernel(const float* __restrict__ bw,
                            const float* __restrict__ bu,
                            float* __restrict__ dst) {
  int i = blockIdx.x * 256 + threadIdx.x;  // 2048
  dst[i] = bw[i] + bu[i];
}

__global__ void zero_flags(unsigned int* __restrict__ p) {
  int i = blockIdx.x * 256 + threadIdx.x;  // 2048
  p[i] = 0u;
}

// ---------------- pipelined merged GEMM (32x32x16) ----------------
// Per wave: one 32x32 z-tile, C2 k-chunks of 16. Per chunk: 1 A-load (16B/l),
// 1 B ds_read (16B/l), 1 MFMA. Phases of 4 chunks; 3-deep A pipeline, counted
// vmcnt 8/4/0. Requires vmcnt==0 at entry; leaves vmcnt==0.
template <int C1, int C2, int M1, int M2>
__device__ __forceinline__ void gemm_run(const unsigned short* __restrict__ a1,
                                         const unsigned short* __restrict__ a2,
                                         const char* bg, int voffA, f32x16& acc) {
  constexpr int NP = C2 / 4;
  bf16x8 av[3][4];
  bf16x8 bb[2][4];

  auto issueA_phase = [&](int q) {
#pragma unroll
    for (int i = 0; i < 4; ++i) {
      int cc = 4 * q + i;
      if (cc < C1)
        ldA<M1>(av[q % 3][i], voffA + cc * 2048, a1);
      else
        ldA<M2>(av[q % 3][i], voffA + (cc - C1) * 2048, a2);
    }
  };
  auto loadB_phase = [&](int q) {
#pragma unroll
    for (int i = 0; i < 4; ++i)
      bb[q & 1][i] = *(const bf16x8*)(bg + (4 * q + i) * 1024);
  };

#pragma unroll
  for (int q = 0; q < 3; ++q)
    if (q < NP) issueA_phase(q);
  loadB_phase(0);

#pragma unroll
  for (int ph = 0; ph < NP; ++ph) {
    if (ph + 1 < NP) loadB_phase(ph + 1);
    if (ph < NP - 2) {
      WAITVM(8);
    } else if (ph == NP - 2) {
      WAITVM(4);
    } else {
      WAITVM(0);
    }
#pragma unroll
    for (int i = 0; i < 4; ++i)
      acc = __builtin_amdgcn_mfma_f32_32x32x16_bf16(av[ph % 3][i],
                                                    bb[ph & 1][i], acc, 0, 0, 0);
    if (ph + 3 < NP) issueA_phase(ph + 3);
  }
}

// ---------------- main persistent kernel ----------------
// grid 128: layer = bid>>5, w = bid&31 (hcols w*16..+16).
// 4 waves: (vm = wv&1 batch half, vn = wv>>1 gate pair).
__global__ void __launch_bounds__(NT, 1)
lstm_main(const unsigned short* __restrict__ xfrag,
          const unsigned short* __restrict__ wf0,
          const unsigned short* __restrict__ wf1,
          const unsigned short* __restrict__ wf2,
          const unsigned short* __restrict__ wf3,
          const float* __restrict__ bias,
          unsigned short* __restrict__ hbuf,
          unsigned int* __restrict__ flags,
          float* __restrict__ out) {
  extern __shared__ char smem[];

  const int bid   = blockIdx.x;
  const int layer = bid >> 5;
  const int w     = bid & 31;
  const int tid   = threadIdx.x;
  const int lane  = tid & 63;
  const int wv    = tid >> 6;
  const int vm    = wv & 1;
  const int vn    = wv >> 1;
  const int C2r   = (layer == 0) ? 48 : 64;
  const int HOFF  = 2 * C2r * 64 * 16;  // zt offset (after weights)

  const unsigned short* wfl =
      (layer == 0) ? wf0 : (layer == 1) ? wf1 : (layer == 2) ? wf2 : wf3;
  const unsigned short* wsl = wfl + (size_t)w * (2 * C2r * 64 * 8);

  // stage weights into LDS (frag-linear; one-time)
  for (int i = tid; i < 2 * C2r * 64; i += NT)
    *(f32x4*)(smem + (size_t)i * 16) = *(const f32x4*)(wsl + (size_t)i * 8);
  __syncthreads();

  const char* bg = smem + ((size_t)vn * C2r * 64 + lane) * 16;
  float* ztf = (float*)(smem + HOFF);  // zt[zz(64)][row-padded 68] f32

  // epilogue thread mapping (tid < 128): b = pvm*32+(plane&31), hc8 = (plane>>5)*8
  const int pvm   = tid >> 6;
  const int plane = tid & 63;
  const int eb    = pvm * 32 + (plane & 31);
  const int ehc8  = (plane >> 5) * 8;

  f32x4 bv4[4][2];
#pragma unroll
  for (int g = 0; g < 4; ++g) {
    const float* bp = bias + layer * 2048 + g * 512 + w * 16 + ehc8;
    bv4[g][0] = *(const f32x4*)bp;
    bv4[g][1] = *(const f32x4*)(bp + 4);
  }

  float creg[8];
#pragma unroll
  for (int r = 0; r < 8; ++r) creg[r] = 0.f;

  const int voffA = lane * 16 + vm * 1024;

  const unsigned short* hprev =
      (layer == 0) ? nullptr : (hbuf + (size_t)(layer - 1) * RING * 32768);
  const unsigned short* hself = hbuf + (size_t)layer * RING * 32768;

  // zt write addressing (per lane)
  const int zz    = vn * 32 + (lane & 31);
  const int rbase = vm * 32 + 4 * (lane >> 5);

  // ---- prologue poll: validate t=0 cross input ----
  if (layer > 0 && wv == 0) {
    const unsigned* fp = flags;
    unsigned need = 0;
    if (lane < 32) {
      fp = flags + ((layer - 1) * 32 + lane) * 16;
      need = 1u;
    }
    while (true) {
      unsigned v = need ? ld_flag(fp) : 0u;
      if (__ballot(need && v < need) == 0) break;
      __builtin_amdgcn_s_sleep(1);
    }
  }
  __syncthreads();
  wait_vm0();

  for (int t = 0; t < 512; ++t) {
    const unsigned short* aW =
        (layer == 0) ? (xfrag + (size_t)t * 16384)
                     : (hprev + (size_t)(t & (RING - 1)) * 32768);
    const unsigned short* aU =
        hself + (size_t)((t - 1) & (RING - 1)) * 32768;

    f32x16 acc = {};

    if (t == 0) {
      if (layer == 0)
        gemm_run<16, 16, 0, 0>(aW, aW, bg, voffA, acc);
      else
        gemm_run<32, 32, 2, 2>(aW, aW, bg, voffA, acc);
    } else {
      if (layer == 0)
        gemm_run<16, 48, 0, 2>(aW, aU, bg, voffA, acc);
      else
        gemm_run<32, 64, 2, 2>(aW, aU, bg, voffA, acc);
    }

    // ---- z -> LDS zt exchange ----
#pragma unroll
    for (int rg = 0; rg < 4; ++rg) {
      f32x4 v = {acc[4 * rg], acc[4 * rg + 1], acc[4 * rg + 2], acc[4 * rg + 3]};
      *(f32x4*)(ztf + zz * 68 + rbase + 8 * rg) = v;
    }
    __syncthreads();

    // ---- gates + state + publish (threads 0..127) ----
    float hreg[8], cnreg[8];
    if (tid < 128) {
      bf16x8 hb;
#pragma unroll
      for (int e = 0; e < 8; ++e) {
        int hc = ehc8 + e;
        float bf_ = (e < 4) ? bv4[0][0][e] : bv4[0][1][e - 4];
        float bi_ = (e < 4) ? bv4[1][0][e] : bv4[1][1][e - 4];
        float bo_ = (e < 4) ? bv4[2][0][e] : bv4[2][1][e - 4];
        float bg_ = (e < 4) ? bv4[3][0][e] : bv4[3][1][e - 4];
        float fg = sigmoid_fast(ztf[(0 + hc) * 68 + eb] + bf_);
        float ig = sigmoid_fast(ztf[(16 + hc) * 68 + eb] + bi_);
        float og = sigmoid_fast(ztf[(32 + hc) * 68 + eb] + bo_);
        float gg = tanh_fast(ztf[(48 + hc) * 68 + eb] + bg_);
        float cn = fg * creg[e] + ig * gg;
        creg[e] = cn;
        cnreg[e] = cn;
        float h = og * tanh_fast(cn);
        hreg[e] = h;
        hb[e] = (short)f2bf(h);
      }
      unsigned short* dst = hbuf +
          ((size_t)layer * RING + (t & (RING - 1))) * 32768 +
          w * 1024 + pvm * 512 + plane * 8;
      st16_coh(dst, __builtin_bit_cast(f32x4, hb));
      wait_vm0();
    }
    __syncthreads();
    if (tid == 0)
      st4_coh(flags + (layer * 32 + w) * 16, (unsigned)(t + 1));

    // ---- output stores (overlap the end-polls below) ----
    if (tid < 128) {
      if (layer == 3) {
        float* op = out + (size_t)eb * 262144 + (size_t)t * 512 + w * 16 + ehc8;
        f32x4 h0 = {hreg[0], hreg[1], hreg[2], hreg[3]};
        f32x4 h1 = {hreg[4], hreg[5], hreg[6], hreg[7]};
        *(f32x4*)op = h0;
        *(f32x4*)(op + 4) = h1;
      }
      if (t == 511) {
        float* hp = out + 16777216 + ((size_t)layer * 64 + eb) * 512 + w * 16 + ehc8;
        float* cp = hp + 131072;
        f32x4 h0 = {hreg[0], hreg[1], hreg[2], hreg[3]};
        f32x4 h1 = {hreg[4], hreg[5], hreg[6], hreg[7]};
        f32x4 c0 = {cnreg[0], cnreg[1], cnreg[2], cnreg[3]};
        f32x4 c1 = {cnreg[4], cnreg[5], cnreg[6], cnreg[7]};
        *(f32x4*)hp = h0;
        *(f32x4*)(hp + 4) = h1;
        *(f32x4*)cp = c0;
        *(f32x4*)(cp + 4) = c1;
      }
    }

    // ---- end polls: validate iteration t+1's inputs ----
    if (t < 511) {
      if (wv == 0) {
        const unsigned* fp = flags;
        unsigned need = 0;
        if (lane < 32) {
          if (layer > 0) {
            fp = flags + ((layer - 1) * 32 + lane) * 16;
            need = (unsigned)(t + 2);
          }
        } else {
          fp = flags + (layer * 32 + (lane - 32)) * 16;
          need = (unsigned)(t + 1);
        }
        while (true) {
          unsigned v = need ? ld_flag(fp) : 0u;
          if (__ballot(need && v < need) == 0) break;
          __builtin_amdgcn_s_sleep(1);
        }
      } else if (wv == 1) {
        const unsigned* fp = flags;
        unsigned need = 0;
        if (lane < 32 && layer < 3 && (t + 1) >= RING) {
          fp = flags + ((layer + 1) * 32 + lane) * 16;
          need = (unsigned)(t + 2 - RING);
        }
        while (true) {
          unsigned v = need ? ld_flag(fp) : 0u;
          if (__ballot(need && v < need) == 0) break;
          __builtin_amdgcn_s_sleep(1);
        }
      }
      __syncthreads();
      wait_vm0();  // out[] stores + poll loads drained: ladder exact at loop top
    }
  }
}

extern "C" void kernel_launch(void* const* d_in, const int* in_sizes, int n_in,
                              void* d_out, int out_size, void* d_ws, size_t ws_size,
                              hipStream_t stream) {
  const float* x = (const float*)d_in[0];
  const float *W[4], *U[4], *bw[4], *bu[4];
  for (int l = 0; l < 4; ++l) {
    W[l]  = (const float*)d_in[1 + 4 * l];
    U[l]  = (const float*)d_in[2 + 4 * l];
    bw[l] = (const float*)d_in[3 + 4 * l];
    bu[l] = (const float*)d_in[4 + 4 * l];
  }

  char* ws = (char*)d_ws;
  unsigned short* xfrag = (unsigned short*)(ws + 0);        // 16,777,216
  unsigned short* wfr0  = (unsigned short*)(ws + 16777216); //  3,145,728
  unsigned short* wfr1  = (unsigned short*)(ws + 19922944); //  4,194,304
  unsigned short* wfr2  = (unsigned short*)(ws + 24117248); //  4,194,304
  unsigned short* wfr3  = (unsigned short*)(ws + 28311552); //  4,194,304
  float*          biasp = (float*)(ws + 32505856);          //     32,768
  unsigned short* hbuf  = (unsigned short*)(ws + 32538624); //  2,097,152
  unsigned int*   flags = (unsigned int*)(ws + 34635776);   //      8,192
  float* out = (float*)d_out;

  cvt_x_kernel<<<4096, 256, 0, stream>>>(x, xfrag);
  cvt_w_kernel<<<768, 256, 0, stream>>>(W[0], U[0], wfr0, 48, 256);
  cvt_w_kernel<<<1024, 256, 0, stream>>>(W[1], U[1], wfr1, 64, 512);
  cvt_w_kernel<<<1024, 256, 0, stream>>>(W[2], U[2], wfr2, 64, 512);
  cvt_w_kernel<<<1024, 256, 0, stream>>>(W[3], U[3], wfr3, 64, 512);
  bias_kernel<<<8, 256, 0, stream>>>(bw[0], bu[0], biasp + 0 * 2048);
  bias_kernel<<<8, 256, 0, stream>>>(bw[1], bu[1], biasp + 1 * 2048);
  bias_kernel<<<8, 256, 0, stream>>>(bw[2], bu[2], biasp + 2 * 2048);
  bias_kernel<<<8, 256, 0, stream>>>(bw[3], bu[3], biasp + 3 * 2048);
  zero_flags<<<8, 256, 0, stream>>>(flags);

  // LDS: weights 2*C2*64*16 (<=131072) + zt 64*68*4 (17408) = 148480
  hipFuncSetAttribute((const void*)lstm_main,
                      hipFuncAttributeMaxDynamicSharedMemorySize, 148480);
  lstm_main<<<dim3(4 * WPL), dim3(NT), 148480, stream>>>(
      xfrag, wfr0, wfr1, wfr2, wfr3, biasp, hbuf, flags, out);
}